// Round 7
// baseline (587.912 us; speedup 1.0000x reference)
//
#include <hip/hip_runtime.h>
#include <hip/hip_fp16.h>

#define N_NODES 50000
#define N_EDGES 800000
#define D_IN_K  500
#define K_PAD   512
#define H_DIM   256
#define N_CLS   7
#define ALPHA_W 0.5f
#define GAMMA_W 0.5f
#define EPS_W   0.1f
#define LN_EPS_W 1e-5f

typedef unsigned short u16;
typedef unsigned int   u32;
typedef _Float16 f16;
typedef __attribute__((ext_vector_type(8))) _Float16 f16x8;
typedef __attribute__((ext_vector_type(4))) float    f32x4;
typedef __attribute__((ext_vector_type(8))) unsigned short u16x8;

__device__ __forceinline__ float h2f(u16 v) {
    __half h;
    *reinterpret_cast<u16*>(&h) = v;
    return __half2float(h);
}
__device__ __forceinline__ u16 f2h(float f) {
    __half h = __float2half_rn(f);
    return *reinterpret_cast<u16*>(&h);
}
__device__ __forceinline__ int clampN(int v) {
    return (v < 0) ? 0 : ((v >= N_NODES) ? N_NODES - 1 : v);
}

// acc[0..7] += c * f16elem(v[0..7]) via v_fma_mix_f32 (no unpack/cvt insts).
__device__ __forceinline__ void fma_mix_row(float* acc, u16x8 v, float c) {
    uint4 p = *reinterpret_cast<const uint4*>(&v);
    asm("v_fma_mix_f32 %0, %1, %2, %0 op_sel:[0,0,0] op_sel_hi:[1,0,0]" : "+v"(acc[0]) : "v"(p.x), "v"(c));
    asm("v_fma_mix_f32 %0, %1, %2, %0 op_sel:[1,0,0] op_sel_hi:[1,0,0]" : "+v"(acc[1]) : "v"(p.x), "v"(c));
    asm("v_fma_mix_f32 %0, %1, %2, %0 op_sel:[0,0,0] op_sel_hi:[1,0,0]" : "+v"(acc[2]) : "v"(p.y), "v"(c));
    asm("v_fma_mix_f32 %0, %1, %2, %0 op_sel:[1,0,0] op_sel_hi:[1,0,0]" : "+v"(acc[3]) : "v"(p.y), "v"(c));
    asm("v_fma_mix_f32 %0, %1, %2, %0 op_sel:[0,0,0] op_sel_hi:[1,0,0]" : "+v"(acc[4]) : "v"(p.z), "v"(c));
    asm("v_fma_mix_f32 %0, %1, %2, %0 op_sel:[1,0,0] op_sel_hi:[1,0,0]" : "+v"(acc[5]) : "v"(p.z), "v"(c));
    asm("v_fma_mix_f32 %0, %1, %2, %0 op_sel:[0,0,0] op_sel_hi:[1,0,0]" : "+v"(acc[6]) : "v"(p.w), "v"(c));
    asm("v_fma_mix_f32 %0, %1, %2, %0 op_sel:[1,0,0] op_sel_hi:[1,0,0]" : "+v"(acc[7]) : "v"(p.w), "v"(c));
}

// ---------------- fallback sentinel (fp32 output) ----------------
__global__ __launch_bounds__(256) void sentinel_kernel(float* out, int n) {
    int i = blockIdx.x * blockDim.x + threadIdx.x;
    if (i < n) out[i] = 2.0f;
}

// ---------------- CSR build ----------------
__global__ __launch_bounds__(256) void zero_kernel(int* p, int n) {
    int i = blockIdx.x * blockDim.x + threadIdx.x;
    if (i < n) p[i] = 0;
}

__global__ __launch_bounds__(256) void hist_kernel(const int* __restrict__ dst, int* __restrict__ deg, int e) {
    int i = blockIdx.x * blockDim.x + threadIdx.x;
    if (i < e) atomicAdd(&deg[clampN(dst[i])], 1);
}

// single-block fused exclusive scan of deg[0..N) -> row_ptr[0..N]
__global__ __launch_bounds__(1024) void scan_fused(const int* __restrict__ deg, int* __restrict__ row_ptr) {
    __shared__ int sdata[1024];
    int t = threadIdx.x;
    const int CH = (N_NODES + 1023) / 1024;   // 49
    int beg = t * CH;
    int end = beg + CH; if (end > N_NODES) end = N_NODES;
    int s = 0;
    for (int j = beg; j < end; j++) s += deg[j];
    sdata[t] = s;
    __syncthreads();
#pragma unroll
    for (int off = 1; off < 1024; off <<= 1) {
        int a = (t >= off) ? sdata[t - off] : 0;
        __syncthreads();
        sdata[t] += a;
        __syncthreads();
    }
    int run = sdata[t] - s;    // exclusive prefix of this chunk
    for (int j = beg; j < end; j++) {
        int d = deg[j];
        row_ptr[j] = run;
        run += d;
    }
    if (t == 1023) row_ptr[N_NODES] = sdata[1023];
}

__global__ __launch_bounds__(256) void scatter_kernel(const int* __restrict__ src, const int* __restrict__ dst,
                                                      const int* __restrict__ row_ptr, int* __restrict__ deg,
                                                      int* __restrict__ srcS, int e) {
    int i = blockIdx.x * blockDim.x + threadIdx.x;
    if (i < e) {
        int d = clampN(dst[i]);
        int old = atomicSub(&deg[d], 1);
        int pos = row_ptr[d] + old - 1;
        if (pos >= 0 && pos < e) srcS[pos] = clampN(src[i]);
    }
}

// ---------------- fp32 -> fp16 conversion for W (k-padded to 512) ----------------
__global__ __launch_bounds__(256) void convert_w(const float* __restrict__ W, f16* __restrict__ W16) {
    int i = blockIdx.x * 256 + threadIdx.x;          // over H_DIM*K_PAD
    int n = i >> 9, k = i & (K_PAD - 1);
    W16[i] = (k < D_IN_K) ? (f16)W[n * D_IN_K + k] : (f16)0.f;
}

// ---------------- init GEMM v6: weight-stationary + 3-buffer LDS + 2-tile raw prefetch.
// Raw float4 regs held unconverted across one iteration so the compiler can't
// pin the waitcnt at issue; cvt+ds_write next iter; ONE barrier per iter
// (mod-3 buffers: writer targets (i+1)%3, slowest reader holds (i-1)%3).
#define GW_STRIDE 520   // f16; 1040 B/row, 16B-aligned
#define GA_BUF    (16 * GW_STRIDE)

__device__ __forceinline__ void raw_load(const float* __restrict__ X, int tile, int r, int sc,
                                         float4& lo, float4& hi) {
    const float* p = X + (long)(tile * 16 + r) * D_IN_K + sc;
    if (sc + 8 <= D_IN_K) {
        lo = *(const float4*)(p);
        hi = *(const float4*)(p + 4);
    } else if (sc < D_IN_K) {            // sc==496: 4 valid + 4 pad
        lo = *(const float4*)(p);
        hi = make_float4(0.f, 0.f, 0.f, 0.f);
    } else {                             // sc==504: all pad
        lo = make_float4(0.f, 0.f, 0.f, 0.f);
        hi = make_float4(0.f, 0.f, 0.f, 0.f);
    }
}
__device__ __forceinline__ f16x8 cvt8(float4 lo, float4 hi) {
    f16x8 v;
    v[0] = (f16)lo.x; v[1] = (f16)lo.y; v[2] = (f16)lo.z; v[3] = (f16)lo.w;
    v[4] = (f16)hi.x; v[5] = (f16)hi.y; v[6] = (f16)hi.z; v[7] = (f16)hi.w;
    return v;
}

__global__ __launch_bounds__(1024) void mfma_gemm6(const float* __restrict__ X,
                                                   const f16* __restrict__ W16,
                                                   const float* __restrict__ bias,
                                                   u16* __restrict__ out) {
    __shared__ __align__(16) f16 alds[3 * GA_BUF];   // 49,920 B

    int tid  = threadIdx.x;
    int w    = tid >> 6;        // wave id = H-tile 0..15
    int lane = tid & 63;
    int m    = lane & 15;
    int quad = lane >> 4;
    int h    = w * 16 + m;

    // persistent B fragments: W rows h, k = kc*32 + quad*8
    f16x8 bfrag[16];
    {
        const f16* wb = W16 + (long)h * K_PAD + quad * 8;
#pragma unroll
        for (int kc = 0; kc < 16; kc++)
            bfrag[kc] = *(const f16x8*)(wb + kc * 32);
    }
    float bv = bias[h];

    int sr = w;                 // staging row
    int sc = lane * 8;          // staging col 0..504

    const int nt = N_NODES / 16;   // 3125
    const int G  = (int)gridDim.x;
    int t = blockIdx.x;

    // prologue: stage tile t directly into buf0; prefetch raw t+G
    {
        float4 lo, hi;
        raw_load(X, t, sr, sc, lo, hi);
        *(f16x8*)&alds[sr * GW_STRIDE + sc] = cvt8(lo, hi);
    }
    float4 lo1, hi1;
    bool h1 = (t + G < nt);
    if (h1) raw_load(X, t + G, sr, sc, lo1, hi1);

    int buf = 0, nbuf = 1;
    while (t < nt) {
        // issue loads for t+2G (stay in flight across this whole iteration)
        bool h2 = (t + 2 * G < nt);
        float4 lo2, hi2;
        if (h2) raw_load(X, t + 2 * G, sr, sc, lo2, hi2);
        // convert+write t+G into nbuf (waits only on lo1/hi1)
        if (h1) *(f16x8*)&alds[nbuf * GA_BUF + sr * GW_STRIDE + sc] = cvt8(lo1, hi1);
        __syncthreads();

        // compute tile t from buf
        f32x4 acc = (f32x4){0.f, 0.f, 0.f, 0.f};
        const f16* ab = &alds[buf * GA_BUF + m * GW_STRIDE + quad * 8];
#pragma unroll
        for (int kc = 0; kc < 16; kc++) {
            f16x8 a = *(const f16x8*)(ab + kc * 32);
            acc = __builtin_amdgcn_mfma_f32_16x16x32_f16(a, bfrag[kc], acc, 0, 0, 0);
        }
        long nb = (long)t * 16 + quad * 4;
#pragma unroll
        for (int r = 0; r < 4; r++)
            out[(nb + r) * H_DIM + h] = f2h(acc[r] + bv);

        lo1 = lo2; hi1 = hi2; h1 = h2;
        t += G;
        buf = nbuf; nbuf = (nbuf + 1) % 3;
    }
}

// ---------------- al/ar for layer 0 (from x0) ----------------
__global__ __launch_bounds__(256) void alar_kernel(const u16* __restrict__ x,
                                                   const float* __restrict__ attl,
                                                   const float* __restrict__ attr,
                                                   float* __restrict__ al, float* __restrict__ ar, int n) {
    int w = (blockIdx.x * blockDim.x + threadIdx.x) >> 6;
    int lane = threadIdx.x & 63;
    if (w >= n) return;
    int col = lane * 4;
    ushort4 xv = *(const ushort4*)(x + (long)w * H_DIM + col);
    float4 lv = *(const float4*)(attl + col);
    float4 rv = *(const float4*)(attr + col);
    float x0 = h2f(xv.x), x1 = h2f(xv.y), x2 = h2f(xv.z), x3 = h2f(xv.w);
    float pl = x0 * lv.x + x1 * lv.y + x2 * lv.z + x3 * lv.w;
    float pr = x0 * rv.x + x1 * rv.y + x2 * rv.z + x3 * rv.w;
#pragma unroll
    for (int off = 32; off >= 1; off >>= 1) {
        pl += __shfl_xor(pl, off);
        pr += __shfl_xor(pr, off);
    }
    if (lane == 0) { al[w] = pl; ar[w] = pr; }
}

// ---------------- layer v5 (best measured: 64 us, 3.66 TB/s): HALF-WAVE PER NODE.
// 32 lanes cover all 256 cols; per-node overhead runs once per wave for TWO
// nodes in parallel; no cross-half reduce. Depth-4 gather (the measured
// optimum: deeper VGPR depth and LDS-DMA both regressed, R5/R6).
__global__ __launch_bounds__(256) void layer_kernel5(const u16* __restrict__ xin,
                                                     const u16* __restrict__ x0,
                                                     const float* __restrict__ alIn,
                                                     float* __restrict__ alOut,
                                                     float* __restrict__ ar,
                                                     const int* __restrict__ row_ptr,
                                                     const int* __restrict__ srcS,
                                                     const float* __restrict__ g,
                                                     const float* __restrict__ b,
                                                     const float* __restrict__ attlN,
                                                     const float* __restrict__ attrN,
                                                     u16* __restrict__ xout,
                                                     const float* __restrict__ Wl,
                                                     const float* __restrict__ bl,
                                                     float* __restrict__ outF,
                                                     int n, int mode) {
    int pair = (blockIdx.x * 256 + threadIdx.x) >> 6;   // wave id
    int lane = threadIdx.x & 63;
    int half = lane >> 5;
    int sub  = lane & 31;
    int w = pair * 2 + half;            // node owned by this half-wave
    if (w >= n) w = n - 1;
    int col = sub * 8;

    float arn = ar[w];
    float aself = ALPHA_W * tanhf(alIn[w] + arn);

    float acc[8];
    {
        u16x8 xs  = *(const u16x8*)(xin + (long)w * H_DIM + col);
        u16x8 x0v = *(const u16x8*)(x0  + (long)w * H_DIM + col);
#pragma unroll
        for (int k = 0; k < 8; k++) acc[k] = aself * h2f(xs[k]) + EPS_W * h2f(x0v[k]);
    }

    int e0 = row_ptr[w], e1 = row_ptr[w + 1];
    int d  = e1 - e0;
    int dmax = max(d, __shfl(d, lane ^ 32));   // wave-uniform

    for (int cb = 0; cb < dmax; cb += 32) {
        int cnt  = d - cb;
        int cmax = dmax - cb; if (cmax > 32) cmax = 32;
        int s = 0; float a = 0.f;
        if (sub < cnt) {
            s = clampN(srcS[e0 + cb + sub]);
            a = GAMMA_W * tanhf(alIn[s] + arn);
        }
        int hb = half << 5;
        for (int j = 0; j < cmax; j += 4) {
            int   s0 = __shfl(s, hb + j),     s1 = __shfl(s, hb + j + 1);
            int   s2 = __shfl(s, hb + j + 2), s3 = __shfl(s, hb + j + 3);
            float c0 = __shfl(a, hb + j),     c1 = __shfl(a, hb + j + 1);
            float c2 = __shfl(a, hb + j + 2), c3 = __shfl(a, hb + j + 3);
            u16x8 v0 = *(const u16x8*)(xin + (long)s0 * H_DIM + col);
            u16x8 v1 = *(const u16x8*)(xin + (long)s1 * H_DIM + col);
            u16x8 v2 = *(const u16x8*)(xin + (long)s2 * H_DIM + col);
            u16x8 v3 = *(const u16x8*)(xin + (long)s3 * H_DIM + col);
            fma_mix_row(acc, v0, c0);
            fma_mix_row(acc, v1, c1);
            fma_mix_row(acc, v2, c2);
            fma_mix_row(acc, v3, c3);
        }
    }

    if (mode == 0) {
        float v[8];
        float sum = 0.f, sq = 0.f;
#pragma unroll
        for (int k = 0; k < 8; k++) {
            v[k] = fmaxf(acc[k], 0.f);
            sum += v[k];
            sq  += v[k] * v[k];
        }
#pragma unroll
        for (int off = 16; off >= 1; off >>= 1) {   // stays within the half
            sum += __shfl_xor(sum, off);
            sq  += __shfl_xor(sq, off);
        }
        float mu = sum * (1.f / 256.f);
        float var = fmaxf(sq * (1.f / 256.f) - mu * mu, 0.f);
        float rstd = rsqrtf(var + LN_EPS_W);
        float4 ga = *(const float4*)(g + col);
        float4 gb = *(const float4*)(g + col + 4);
        float4 ba = *(const float4*)(b + col);
        float4 bb = *(const float4*)(b + col + 4);
        float gg[8]  = {ga.x, ga.y, ga.z, ga.w, gb.x, gb.y, gb.z, gb.w};
        float bbv[8] = {ba.x, ba.y, ba.z, ba.w, bb.x, bb.y, bb.z, bb.w};
        float4 la = *(const float4*)(attlN + col);
        float4 lb = *(const float4*)(attlN + col + 4);
        float4 ra = *(const float4*)(attrN + col);
        float4 rb = *(const float4*)(attrN + col + 4);
        float ll[8] = {la.x, la.y, la.z, la.w, lb.x, lb.y, lb.z, lb.w};
        float rr[8] = {ra.x, ra.y, ra.z, ra.w, rb.x, rb.y, rb.z, rb.w};
        float pl = 0.f, pr = 0.f;
        u16x8 o;
#pragma unroll
        for (int k = 0; k < 8; k++) {
            float val = (v[k] - mu) * rstd * gg[k] + bbv[k];
            o[k] = f2h(val);
            pl += val * ll[k];
            pr += val * rr[k];
        }
#pragma unroll
        for (int off = 16; off >= 1; off >>= 1) {
            pl += __shfl_xor(pl, off);
            pr += __shfl_xor(pr, off);
        }
        if (sub == 0) { alOut[w] = pl; ar[w] = pr; }
        *(u16x8*)(xout + (long)w * H_DIM + col) = o;
    } else {
        float p[N_CLS];
#pragma unroll
        for (int c = 0; c < N_CLS; c++) {
            const float* wr = Wl + c * H_DIM + col;
            float4 wa = *(const float4*)(wr);
            float4 wb = *(const float4*)(wr + 4);
            p[c] = acc[0] * wa.x + acc[1] * wa.y + acc[2] * wa.z + acc[3] * wa.w
                 + acc[4] * wb.x + acc[5] * wb.y + acc[6] * wb.z + acc[7] * wb.w;
        }
#pragma unroll
        for (int off = 16; off >= 1; off >>= 1) {      // within-half reduce
#pragma unroll
            for (int c = 0; c < N_CLS; c++) p[c] += __shfl_xor(p[c], off);
        }
        if (sub == 0) {
            float e[N_CLS];
            float m = -1e30f;
#pragma unroll
            for (int c = 0; c < N_CLS; c++) {
                e[c] = p[c] + bl[c];
                m = fmaxf(m, e[c]);
            }
            float sx = 0.f;
#pragma unroll
            for (int c = 0; c < N_CLS; c++) sx += expf(e[c] - m);
            float lse = logf(sx);
#pragma unroll
            for (int c = 0; c < N_CLS; c++) {
                outF[(long)w * N_CLS + c] = e[c];
                outF[(long)N_NODES * N_CLS + (long)w * N_CLS + c] = e[c] - m - lse;
            }
        }
    }
}

extern "C" void kernel_launch(void* const* d_in, const int* in_sizes, int n_in,
                              void* d_out, int out_size, void* d_ws, size_t ws_size,
                              hipStream_t stream) {
    const float* x_in   = (const float*)d_in[0];
    const int*   ei     = (const int*)d_in[1];     // [2][E] planar int32
    const float* W_init = (const float*)d_in[2];
    const float* b_init = (const float*)d_in[3];
    const float* att_l  = (const float*)d_in[4];
    const float* att_r  = (const float*)d_in[5];
    const float* ln_g   = (const float*)d_in[6];
    const float* ln_b   = (const float*)d_in[7];
    const float* W_last = (const float*)d_in[8];
    const float* b_last = (const float*)d_in[9];
    float* out = (float*)d_out;

    // workspace layout (80,802,112 B total)
    const size_t OFF_X0  = 0;                  // 25,600,000
    const size_t OFF_XA  = 25600000;           // 25,600,000
    const size_t OFF_XB  = 51200000;           // 25,600,000
    const size_t OFF_AL  = 76800000;           //    200,000 (W16 overlays AL/AR during init)
    const size_t OFF_AR  = 77000000;           //    200,000
    const size_t OFF_DEG = 77200000;           //    200,000 (al2 after CSR build)
    const size_t OFF_RP  = 77400000;           //    200,064
    const size_t OFF_SRC = 77600064;           //  3,200,000
    const size_t OFF_BS  = 80800064;           //      1,024
    const size_t OFF_BO  = 80801088;           //      1,024
    const size_t WS_NEED = 80802112;

    if (ws_size < WS_NEED) {
        sentinel_kernel<<<(out_size + 255) / 256, 256, 0, stream>>>(out, out_size);
        return;
    }

    char* ws = (char*)d_ws;
    u16* x0  = (u16*)(ws + OFF_X0);
    u16* xA  = (u16*)(ws + OFF_XA);
    u16* xB  = (u16*)(ws + OFF_XB);
    f16* W16 = (f16*)(ws + OFF_AL);
    float* al  = (float*)(ws + OFF_AL);
    float* ar  = (float*)(ws + OFF_AR);
    float* al2 = (float*)(ws + OFF_DEG);
    int* deg     = (int*)(ws + OFF_DEG);
    int* row_ptr = (int*)(ws + OFF_RP);
    int* srcS    = (int*)(ws + OFF_SRC);

    const int* e_src = ei;
    const int* e_dst = ei + N_EDGES;

    // --- CSR build (by dst): zero + hist + fused single-block scan + scatter ---
    int zb = (N_NODES + 255) / 256;
    zero_kernel<<<zb, 256, 0, stream>>>(deg, N_NODES);
    int eb = (N_EDGES + 255) / 256;
    hist_kernel<<<eb, 256, 0, stream>>>(e_dst, deg, N_EDGES);
    scan_fused<<<1, 1024, 0, stream>>>(deg, row_ptr);
    scatter_kernel<<<eb, 256, 0, stream>>>(e_src, e_dst, row_ptr, deg, srcS, N_EDGES);

    // --- init linear: W convert + MFMA GEMM v6 (weight-stationary, 3-buf, 2-ahead) ---
    convert_w<<<(H_DIM * K_PAD) / 256, 256, 0, stream>>>(W_init, W16);
    mfma_gemm6<<<256, 1024, 0, stream>>>(x_in, W16, b_init, x0);

    // --- al/ar for layer 0 ---
    int nb = (N_NODES * 64 + 255) / 256;   // one wave per node
    alar_kernel<<<nb, 256, 0, stream>>>(x0, att_l, att_r, al, ar, N_NODES);

    // --- layers 0-2 (LN mode), layer 3 (fused final); 2 nodes/wave, 8 nodes/block ---
    int lb = (N_NODES + 7) / 8;            // 6250
    const u16* bufs_in[4]   = {x0, xA, xB, xA};
    u16* bufs_out[4]        = {xA, xB, xA, xB};   // [3] unused
    const float* al_in[4]   = {al, al2, al, al2};
    float* al_out[4]        = {al2, al, al2, al};
    for (int i = 0; i < 4; i++) {
        int nxt = (i < 3) ? (i + 1) : i;
        layer_kernel5<<<lb, 256, 0, stream>>>(bufs_in[i], x0, al_in[i], al_out[i], ar,
                                              row_ptr, srcS,
                                              ln_g + i * H_DIM, ln_b + i * H_DIM,
                                              att_l + nxt * H_DIM, att_r + nxt * H_DIM,
                                              bufs_out[i], W_last, b_last, out,
                                              N_NODES, (i < 3) ? 0 : 1);
    }
}

// Round 8
// 519.426 us; speedup vs baseline: 1.1318x; 1.1318x over previous
//
#include <hip/hip_runtime.h>
#include <hip/hip_fp16.h>

#define N_NODES 50000
#define N_EDGES 800000
#define D_IN_K  500
#define K_PAD   512
#define H_DIM   256
#define N_CLS   7
#define ALPHA_W 0.5f
#define GAMMA_W 0.5f
#define EPS_W   0.1f
#define LN_EPS_W 1e-5f

#define SCAN_B 256
#define SCAN_NB ((N_NODES + SCAN_B - 1) / SCAN_B)   // 196

typedef unsigned short u16;
typedef unsigned int   u32;
typedef _Float16 f16;
typedef __attribute__((ext_vector_type(8))) _Float16 f16x8;
typedef __attribute__((ext_vector_type(4))) float    f32x4;
typedef __attribute__((ext_vector_type(8))) unsigned short u16x8;

__device__ __forceinline__ float h2f(u16 v) {
    __half h;
    *reinterpret_cast<u16*>(&h) = v;
    return __half2float(h);
}
__device__ __forceinline__ u16 f2h(float f) {
    __half h = __float2half_rn(f);
    return *reinterpret_cast<u16*>(&h);
}
__device__ __forceinline__ int clampN(int v) {
    return (v < 0) ? 0 : ((v >= N_NODES) ? N_NODES - 1 : v);
}

// acc[0..7] += c * f16elem(v[0..7]) via v_fma_mix_f32 (no unpack/cvt insts).
__device__ __forceinline__ void fma_mix_row(float* acc, u16x8 v, float c) {
    uint4 p = *reinterpret_cast<const uint4*>(&v);
    asm("v_fma_mix_f32 %0, %1, %2, %0 op_sel:[0,0,0] op_sel_hi:[1,0,0]" : "+v"(acc[0]) : "v"(p.x), "v"(c));
    asm("v_fma_mix_f32 %0, %1, %2, %0 op_sel:[1,0,0] op_sel_hi:[1,0,0]" : "+v"(acc[1]) : "v"(p.x), "v"(c));
    asm("v_fma_mix_f32 %0, %1, %2, %0 op_sel:[0,0,0] op_sel_hi:[1,0,0]" : "+v"(acc[2]) : "v"(p.y), "v"(c));
    asm("v_fma_mix_f32 %0, %1, %2, %0 op_sel:[1,0,0] op_sel_hi:[1,0,0]" : "+v"(acc[3]) : "v"(p.y), "v"(c));
    asm("v_fma_mix_f32 %0, %1, %2, %0 op_sel:[0,0,0] op_sel_hi:[1,0,0]" : "+v"(acc[4]) : "v"(p.z), "v"(c));
    asm("v_fma_mix_f32 %0, %1, %2, %0 op_sel:[1,0,0] op_sel_hi:[1,0,0]" : "+v"(acc[5]) : "v"(p.z), "v"(c));
    asm("v_fma_mix_f32 %0, %1, %2, %0 op_sel:[0,0,0] op_sel_hi:[1,0,0]" : "+v"(acc[6]) : "v"(p.w), "v"(c));
    asm("v_fma_mix_f32 %0, %1, %2, %0 op_sel:[1,0,0] op_sel_hi:[1,0,0]" : "+v"(acc[7]) : "v"(p.w), "v"(c));
}

// ---------------- fallback sentinel (fp32 output) ----------------
__global__ __launch_bounds__(256) void sentinel_kernel(float* out, int n) {
    int i = blockIdx.x * blockDim.x + threadIdx.x;
    if (i < n) out[i] = 2.0f;
}

// ---------------- CSR build ----------------
__global__ __launch_bounds__(256) void zero_kernel(int* p, int n) {
    int i = blockIdx.x * blockDim.x + threadIdx.x;
    if (i < n) p[i] = 0;
}

__global__ __launch_bounds__(256) void hist_kernel(const int* __restrict__ dst, int* __restrict__ deg, int e) {
    int i = blockIdx.x * blockDim.x + threadIdx.x;
    if (i < e) atomicAdd(&deg[clampN(dst[i])], 1);
}

__global__ __launch_bounds__(SCAN_B) void scan_a(const int* __restrict__ deg, int* __restrict__ row_ptr,
                                                 int* __restrict__ bsum) {
    __shared__ int sdata[SCAN_B];
    int t = threadIdx.x;
    int i = blockIdx.x * SCAN_B + t;
    int v = (i < N_NODES) ? deg[i] : 0;
    sdata[t] = v;
    __syncthreads();
#pragma unroll
    for (int off = 1; off < SCAN_B; off <<= 1) {
        int a = (t >= off) ? sdata[t - off] : 0;
        __syncthreads();
        sdata[t] += a;
        __syncthreads();
    }
    if (i < N_NODES) row_ptr[i] = sdata[t] - v;
    if (t == SCAN_B - 1) bsum[blockIdx.x] = sdata[t];
}

__global__ __launch_bounds__(SCAN_B) void scan_b(int* __restrict__ bsum, int* __restrict__ boff,
                                                 int* __restrict__ row_ptr) {
    __shared__ int sdata[SCAN_B];
    int t = threadIdx.x;
    int v = (t < SCAN_NB) ? bsum[t] : 0;
    sdata[t] = v;
    __syncthreads();
#pragma unroll
    for (int off = 1; off < SCAN_B; off <<= 1) {
        int a = (t >= off) ? sdata[t - off] : 0;
        __syncthreads();
        sdata[t] += a;
        __syncthreads();
    }
    if (t < SCAN_NB) boff[t] = sdata[t] - v;
    if (t == SCAN_B - 1) row_ptr[N_NODES] = sdata[t];
}

__global__ __launch_bounds__(SCAN_B) void scan_c(int* __restrict__ row_ptr, const int* __restrict__ boff) {
    int i = blockIdx.x * SCAN_B + threadIdx.x;
    if (i < N_NODES) row_ptr[i] += boff[blockIdx.x];
}

__global__ __launch_bounds__(256) void scatter_kernel(const int* __restrict__ src, const int* __restrict__ dst,
                                                      const int* __restrict__ row_ptr, int* __restrict__ deg,
                                                      int* __restrict__ srcS, int e) {
    int i = blockIdx.x * blockDim.x + threadIdx.x;
    if (i < e) {
        int d = clampN(dst[i]);
        int old = atomicSub(&deg[d], 1);
        int pos = row_ptr[d] + old - 1;
        if (pos >= 0 && pos < e) srcS[pos] = clampN(src[i]);
    }
}

// ---------------- fp32 -> fp16 conversion for W (k-padded to 512) ----------------
__global__ __launch_bounds__(256) void convert_w(const float* __restrict__ W, f16* __restrict__ W16) {
    int i = blockIdx.x * 256 + threadIdx.x;          // over H_DIM*K_PAD
    int n = i >> 9, k = i & (K_PAD - 1);
    W16[i] = (k < D_IN_K) ? (f16)W[n * D_IN_K + k] : (f16)0.f;
}

// ---------------- init GEMM v6: weight-stationary + 3-buffer LDS + 2-tile raw prefetch ----------------
#define GW_STRIDE 520   // f16; 1040 B/row, 16B-aligned
#define GA_BUF    (16 * GW_STRIDE)

__device__ __forceinline__ void raw_load(const float* __restrict__ X, int tile, int r, int sc,
                                         float4& lo, float4& hi) {
    const float* p = X + (long)(tile * 16 + r) * D_IN_K + sc;
    if (sc + 8 <= D_IN_K) {
        lo = *(const float4*)(p);
        hi = *(const float4*)(p + 4);
    } else if (sc < D_IN_K) {            // sc==496: 4 valid + 4 pad
        lo = *(const float4*)(p);
        hi = make_float4(0.f, 0.f, 0.f, 0.f);
    } else {                             // sc==504: all pad
        lo = make_float4(0.f, 0.f, 0.f, 0.f);
        hi = make_float4(0.f, 0.f, 0.f, 0.f);
    }
}
__device__ __forceinline__ f16x8 cvt8(float4 lo, float4 hi) {
    f16x8 v;
    v[0] = (f16)lo.x; v[1] = (f16)lo.y; v[2] = (f16)lo.z; v[3] = (f16)lo.w;
    v[4] = (f16)hi.x; v[5] = (f16)hi.y; v[6] = (f16)hi.z; v[7] = (f16)hi.w;
    return v;
}

__global__ __launch_bounds__(1024) void mfma_gemm6(const float* __restrict__ X,
                                                   const f16* __restrict__ W16,
                                                   const float* __restrict__ bias,
                                                   u16* __restrict__ out) {
    __shared__ __align__(16) f16 alds[3 * GA_BUF];   // 49,920 B

    int tid  = threadIdx.x;
    int w    = tid >> 6;        // wave id = H-tile 0..15
    int lane = tid & 63;
    int m    = lane & 15;
    int quad = lane >> 4;
    int h    = w * 16 + m;

    // persistent B fragments: W rows h, k = kc*32 + quad*8
    f16x8 bfrag[16];
    {
        const f16* wb = W16 + (long)h * K_PAD + quad * 8;
#pragma unroll
        for (int kc = 0; kc < 16; kc++)
            bfrag[kc] = *(const f16x8*)(wb + kc * 32);
    }
    float bv = bias[h];

    int sr = w;                 // staging row
    int sc = lane * 8;          // staging col 0..504

    const int nt = N_NODES / 16;   // 3125
    const int G  = (int)gridDim.x;
    int t = blockIdx.x;

    // prologue: stage tile t directly into buf0; prefetch raw t+G
    {
        float4 lo, hi;
        raw_load(X, t, sr, sc, lo, hi);
        *(f16x8*)&alds[sr * GW_STRIDE + sc] = cvt8(lo, hi);
    }
    float4 lo1, hi1;
    bool h1 = (t + G < nt);
    if (h1) raw_load(X, t + G, sr, sc, lo1, hi1);

    int buf = 0, nbuf = 1;
    while (t < nt) {
        // issue loads for t+2G (stay in flight across this whole iteration)
        bool h2 = (t + 2 * G < nt);
        float4 lo2, hi2;
        if (h2) raw_load(X, t + 2 * G, sr, sc, lo2, hi2);
        // convert+write t+G into nbuf (waits only on lo1/hi1)
        if (h1) *(f16x8*)&alds[nbuf * GA_BUF + sr * GW_STRIDE + sc] = cvt8(lo1, hi1);
        __syncthreads();

        // compute tile t from buf
        f32x4 acc = (f32x4){0.f, 0.f, 0.f, 0.f};
        const f16* ab = &alds[buf * GA_BUF + m * GW_STRIDE + quad * 8];
#pragma unroll
        for (int kc = 0; kc < 16; kc++) {
            f16x8 a = *(const f16x8*)(ab + kc * 32);
            acc = __builtin_amdgcn_mfma_f32_16x16x32_f16(a, bfrag[kc], acc, 0, 0, 0);
        }
        long nb = (long)t * 16 + quad * 4;
#pragma unroll
        for (int r = 0; r < 4; r++)
            out[(nb + r) * H_DIM + h] = f2h(acc[r] + bv);

        lo1 = lo2; hi1 = hi2; h1 = h2;
        t += G;
        buf = nbuf; nbuf = (nbuf + 1) % 3;
    }
}

// ---------------- al/ar for layer 0 (from x0) ----------------
__global__ __launch_bounds__(256) void alar_kernel(const u16* __restrict__ x,
                                                   const float* __restrict__ attl,
                                                   const float* __restrict__ attr,
                                                   float* __restrict__ al, float* __restrict__ ar, int n) {
    int w = (blockIdx.x * blockDim.x + threadIdx.x) >> 6;
    int lane = threadIdx.x & 63;
    if (w >= n) return;
    int col = lane * 4;
    ushort4 xv = *(const ushort4*)(x + (long)w * H_DIM + col);
    float4 lv = *(const float4*)(attl + col);
    float4 rv = *(const float4*)(attr + col);
    float x0 = h2f(xv.x), x1 = h2f(xv.y), x2 = h2f(xv.z), x3 = h2f(xv.w);
    float pl = x0 * lv.x + x1 * lv.y + x2 * lv.z + x3 * lv.w;
    float pr = x0 * rv.x + x1 * rv.y + x2 * rv.z + x3 * rv.w;
#pragma unroll
    for (int off = 32; off >= 1; off >>= 1) {
        pl += __shfl_xor(pl, off);
        pr += __shfl_xor(pr, off);
    }
    if (lane == 0) { al[w] = pl; ar[w] = pr; }
}

// ---------------- layer v5 (best measured: 64 us, 3.66 TB/s): HALF-WAVE PER NODE ----------------
__global__ __launch_bounds__(256) void layer_kernel5(const u16* __restrict__ xin,
                                                     const u16* __restrict__ x0,
                                                     const float* __restrict__ alIn,
                                                     float* __restrict__ alOut,
                                                     float* __restrict__ ar,
                                                     const int* __restrict__ row_ptr,
                                                     const int* __restrict__ srcS,
                                                     const float* __restrict__ g,
                                                     const float* __restrict__ b,
                                                     const float* __restrict__ attlN,
                                                     const float* __restrict__ attrN,
                                                     u16* __restrict__ xout,
                                                     const float* __restrict__ Wl,
                                                     const float* __restrict__ bl,
                                                     float* __restrict__ outF,
                                                     int n, int mode) {
    int pair = (blockIdx.x * 256 + threadIdx.x) >> 6;   // wave id
    int lane = threadIdx.x & 63;
    int half = lane >> 5;
    int sub  = lane & 31;
    int w = pair * 2 + half;            // node owned by this half-wave
    if (w >= n) w = n - 1;
    int col = sub * 8;

    float arn = ar[w];
    float aself = ALPHA_W * tanhf(alIn[w] + arn);

    float acc[8];
    {
        u16x8 xs  = *(const u16x8*)(xin + (long)w * H_DIM + col);
        u16x8 x0v = *(const u16x8*)(x0  + (long)w * H_DIM + col);
#pragma unroll
        for (int k = 0; k < 8; k++) acc[k] = aself * h2f(xs[k]) + EPS_W * h2f(x0v[k]);
    }

    int e0 = row_ptr[w], e1 = row_ptr[w + 1];
    int d  = e1 - e0;
    int dmax = max(d, __shfl(d, lane ^ 32));   // wave-uniform

    for (int cb = 0; cb < dmax; cb += 32) {
        int cnt  = d - cb;
        int cmax = dmax - cb; if (cmax > 32) cmax = 32;
        int s = 0; float a = 0.f;
        if (sub < cnt) {
            s = clampN(srcS[e0 + cb + sub]);
            a = GAMMA_W * tanhf(alIn[s] + arn);
        }
        int hb = half << 5;
        for (int j = 0; j < cmax; j += 4) {
            int   s0 = __shfl(s, hb + j),     s1 = __shfl(s, hb + j + 1);
            int   s2 = __shfl(s, hb + j + 2), s3 = __shfl(s, hb + j + 3);
            float c0 = __shfl(a, hb + j),     c1 = __shfl(a, hb + j + 1);
            float c2 = __shfl(a, hb + j + 2), c3 = __shfl(a, hb + j + 3);
            u16x8 v0 = *(const u16x8*)(xin + (long)s0 * H_DIM + col);
            u16x8 v1 = *(const u16x8*)(xin + (long)s1 * H_DIM + col);
            u16x8 v2 = *(const u16x8*)(xin + (long)s2 * H_DIM + col);
            u16x8 v3 = *(const u16x8*)(xin + (long)s3 * H_DIM + col);
            fma_mix_row(acc, v0, c0);
            fma_mix_row(acc, v1, c1);
            fma_mix_row(acc, v2, c2);
            fma_mix_row(acc, v3, c3);
        }
    }

    if (mode == 0) {
        float v[8];
        float sum = 0.f, sq = 0.f;
#pragma unroll
        for (int k = 0; k < 8; k++) {
            v[k] = fmaxf(acc[k], 0.f);
            sum += v[k];
            sq  += v[k] * v[k];
        }
#pragma unroll
        for (int off = 16; off >= 1; off >>= 1) {   // stays within the half
            sum += __shfl_xor(sum, off);
            sq  += __shfl_xor(sq, off);
        }
        float mu = sum * (1.f / 256.f);
        float var = fmaxf(sq * (1.f / 256.f) - mu * mu, 0.f);
        float rstd = rsqrtf(var + LN_EPS_W);
        float4 ga = *(const float4*)(g + col);
        float4 gb = *(const float4*)(g + col + 4);
        float4 ba = *(const float4*)(b + col);
        float4 bb = *(const float4*)(b + col + 4);
        float gg[8]  = {ga.x, ga.y, ga.z, ga.w, gb.x, gb.y, gb.z, gb.w};
        float bbv[8] = {ba.x, ba.y, ba.z, ba.w, bb.x, bb.y, bb.z, bb.w};
        float4 la = *(const float4*)(attlN + col);
        float4 lb = *(const float4*)(attlN + col + 4);
        float4 ra = *(const float4*)(attrN + col);
        float4 rb = *(const float4*)(attrN + col + 4);
        float ll[8] = {la.x, la.y, la.z, la.w, lb.x, lb.y, lb.z, lb.w};
        float rr[8] = {ra.x, ra.y, ra.z, ra.w, rb.x, rb.y, rb.z, rb.w};
        float pl = 0.f, pr = 0.f;
        u16x8 o;
#pragma unroll
        for (int k = 0; k < 8; k++) {
            float val = (v[k] - mu) * rstd * gg[k] + bbv[k];
            o[k] = f2h(val);
            pl += val * ll[k];
            pr += val * rr[k];
        }
#pragma unroll
        for (int off = 16; off >= 1; off >>= 1) {
            pl += __shfl_xor(pl, off);
            pr += __shfl_xor(pr, off);
        }
        if (sub == 0) { alOut[w] = pl; ar[w] = pr; }
        *(u16x8*)(xout + (long)w * H_DIM + col) = o;
    } else {
        float p[N_CLS];
#pragma unroll
        for (int c = 0; c < N_CLS; c++) {
            const float* wr = Wl + c * H_DIM + col;
            float4 wa = *(const float4*)(wr);
            float4 wb = *(const float4*)(wr + 4);
            p[c] = acc[0] * wa.x + acc[1] * wa.y + acc[2] * wa.z + acc[3] * wa.w
                 + acc[4] * wb.x + acc[5] * wb.y + acc[6] * wb.z + acc[7] * wb.w;
        }
#pragma unroll
        for (int off = 16; off >= 1; off >>= 1) {      // within-half reduce
#pragma unroll
            for (int c = 0; c < N_CLS; c++) p[c] += __shfl_xor(p[c], off);
        }
        if (sub == 0) {
            float e[N_CLS];
            float m = -1e30f;
#pragma unroll
            for (int c = 0; c < N_CLS; c++) {
                e[c] = p[c] + bl[c];
                m = fmaxf(m, e[c]);
            }
            float sx = 0.f;
#pragma unroll
            for (int c = 0; c < N_CLS; c++) sx += expf(e[c] - m);
            float lse = logf(sx);
#pragma unroll
            for (int c = 0; c < N_CLS; c++) {
                outF[(long)w * N_CLS + c] = e[c];
                outF[(long)N_NODES * N_CLS + (long)w * N_CLS + c] = e[c] - m - lse;
            }
        }
    }
}

extern "C" void kernel_launch(void* const* d_in, const int* in_sizes, int n_in,
                              void* d_out, int out_size, void* d_ws, size_t ws_size,
                              hipStream_t stream) {
    const float* x_in   = (const float*)d_in[0];
    const int*   ei     = (const int*)d_in[1];     // [2][E] planar int32
    const float* W_init = (const float*)d_in[2];
    const float* b_init = (const float*)d_in[3];
    const float* att_l  = (const float*)d_in[4];
    const float* att_r  = (const float*)d_in[5];
    const float* ln_g   = (const float*)d_in[6];
    const float* ln_b   = (const float*)d_in[7];
    const float* W_last = (const float*)d_in[8];
    const float* b_last = (const float*)d_in[9];
    float* out = (float*)d_out;

    // workspace layout (80,802,112 B total)
    const size_t OFF_X0  = 0;                  // 25,600,000
    const size_t OFF_XA  = 25600000;           // 25,600,000
    const size_t OFF_XB  = 51200000;           // 25,600,000
    const size_t OFF_AL  = 76800000;           //    200,000 (W16 overlays AL/AR during init)
    const size_t OFF_AR  = 77000000;           //    200,000
    const size_t OFF_DEG = 77200000;           //    200,000 (al2 after CSR build)
    const size_t OFF_RP  = 77400000;           //    200,064
    const size_t OFF_SRC = 77600064;           //  3,200,000
    const size_t OFF_BS  = 80800064;           //      1,024
    const size_t OFF_BO  = 80801088;           //      1,024
    const size_t WS_NEED = 80802112;

    if (ws_size < WS_NEED) {
        sentinel_kernel<<<(out_size + 255) / 256, 256, 0, stream>>>(out, out_size);
        return;
    }

    char* ws = (char*)d_ws;
    u16* x0  = (u16*)(ws + OFF_X0);
    u16* xA  = (u16*)(ws + OFF_XA);
    u16* xB  = (u16*)(ws + OFF_XB);
    f16* W16 = (f16*)(ws + OFF_AL);
    float* al  = (float*)(ws + OFF_AL);
    float* ar  = (float*)(ws + OFF_AR);
    float* al2 = (float*)(ws + OFF_DEG);
    int* deg     = (int*)(ws + OFF_DEG);
    int* row_ptr = (int*)(ws + OFF_RP);
    int* srcS    = (int*)(ws + OFF_SRC);
    int* bsum    = (int*)(ws + OFF_BS);
    int* boff    = (int*)(ws + OFF_BO);

    const int* e_src = ei;
    const int* e_dst = ei + N_EDGES;

    // --- CSR build (by dst), two-level scan (proven fast; fused scan was 77us, R7) ---
    int zb = (N_NODES + 255) / 256;
    zero_kernel<<<zb, 256, 0, stream>>>(deg, N_NODES);
    int eb = (N_EDGES + 255) / 256;
    hist_kernel<<<eb, 256, 0, stream>>>(e_dst, deg, N_EDGES);
    scan_a<<<SCAN_NB, SCAN_B, 0, stream>>>(deg, row_ptr, bsum);
    scan_b<<<1, SCAN_B, 0, stream>>>(bsum, boff, row_ptr);
    scan_c<<<SCAN_NB, SCAN_B, 0, stream>>>(row_ptr, boff);
    scatter_kernel<<<eb, 256, 0, stream>>>(e_src, e_dst, row_ptr, deg, srcS, N_EDGES);

    // --- init linear: W convert + MFMA GEMM v6 (weight-stationary, 3-buf, 2-ahead) ---
    convert_w<<<(H_DIM * K_PAD) / 256, 256, 0, stream>>>(W_init, W16);
    mfma_gemm6<<<256, 1024, 0, stream>>>(x_in, W16, b_init, x0);

    // --- al/ar for layer 0 ---
    int nb = (N_NODES * 64 + 255) / 256;   // one wave per node
    alar_kernel<<<nb, 256, 0, stream>>>(x0, att_l, att_r, al, ar, N_NODES);

    // --- layers 0-2 (LN mode), layer 3 (fused final); 2 nodes/wave, 8 nodes/block ---
    int lb = (N_NODES + 7) / 8;            // 6250
    const u16* bufs_in[4]   = {x0, xA, xB, xA};
    u16* bufs_out[4]        = {xA, xB, xA, xB};   // [3] unused
    const float* al_in[4]   = {al, al2, al, al2};
    float* al_out[4]        = {al2, al, al2, al};
    for (int i = 0; i < 4; i++) {
        int nxt = (i < 3) ? (i + 1) : i;
        layer_kernel5<<<lb, 256, 0, stream>>>(bufs_in[i], x0, al_in[i], al_out[i], ar,
                                              row_ptr, srcS,
                                              ln_g + i * H_DIM, ln_b + i * H_DIM,
                                              att_l + nxt * H_DIM, att_r + nxt * H_DIM,
                                              bufs_out[i], W_last, b_last, out,
                                              N_NODES, (i < 3) ? 0 : 1);
    }
}